// Round 14
// baseline (205.321 us; speedup 1.0000x reference)
//
#include <hip/hip_runtime.h>
#include <cstdint>

#define NPRED 25200      // total predictions (8400 positions * 3 anchors)
#define NPOS  8400
#define NCLS  80
#define CAP   512        // max boxes per class (mean ~315, sigma ~18)
#define MW    8          // u64 mask words per row (512/64)
#define MSTRIDE 514      // mask row stride (u64): 514*8 B == 4 banks offset/word -> no 32-way conflict
#define NCHUNK 132       // 64-position chunks: 100 (s0) + 25 (s1) + 7 (s2 tail)

__device__ __forceinline__ float sigmoidf_(float x) { return 1.0f / (1.0f + expf(-x)); }

// Block = (64-position chunk, anchor), 64 threads. REGISTER-RESIDENT class
// logits (v[80] in VGPRs; (64,2) bounds -> 256 VGPR cap, no spill).
// Measured ~4.5us (R12 4x-replication attribution). Op order exact.
__global__ __launch_bounds__(64, 2) void decode_kernel(
    const float* __restrict__ ps, const float* __restrict__ pm, const float* __restrict__ pl,
    float* __restrict__ out,
    float4* __restrict__ g_boxin, uint64_t* __restrict__ g_key)
{
    int chunk = blockIdx.x;
    int a     = blockIdx.y;
    int t     = threadIdx.x;

    const float* p; int HW, W, base, si; float stride; int w0;
    if (chunk < 100)      { p = ps; HW = 6400; W = 80; stride = 8.f;  base = 0;    si = 0; w0 = chunk * 64; }
    else if (chunk < 125) { p = pm; HW = 1600; W = 40; stride = 16.f; base = 6400; si = 1; w0 = (chunk - 100) * 64; }
    else                  { p = pl; HW = 400;  W = 20; stride = 32.f; base = 8000; si = 2; w0 = (chunk - 125) * 64; }

    int local = w0 + t;
    bool valid = local < HW;
    int lclamp = valid ? local : (HW - 1);

    const float* cbase = p + (size_t)(3 + a * NCLS) * HW + lclamp;
    float v[NCLS];
#pragma unroll
    for (int c = 0; c < NCLS; c++) v[c] = cbase[(size_t)c * HW];

    float objl = p[(size_t)a * HW + lclamp];
    const float* rb = p + (size_t)(3 + 3 * NCLS + a * 4) * HW + lclamp;
    float tx = rb[0], ty = rb[(size_t)HW], tw = rb[(size_t)2 * HW], th = rb[(size_t)3 * HW];

    // pass A: max (ascending, order-exact)
    float m = -INFINITY;
#pragma unroll
    for (int c = 0; c < NCLS; c++) m = fmaxf(m, v[c]);
    // pass B: serial ascending sum + argmax of e (strict >, ascending)
    float s = 0.f; float beste = -1.f; int bi = 0;
#pragma unroll
    for (int c = 0; c < NCLS; c++) {
        float e = expf(v[c] - m);
        s += e;
        if (e > beste) { beste = e; bi = c; }
    }
    float obj = sigmoidf_(objl);
    float best = beste / s * obj;             // == ref's (e/s)*obj at argmax

    if (!valid) return;

    const float AW[9] = {10.f,16.f,33.f, 30.f,62.f,59.f, 116.f,156.f,373.f};
    const float AH[9] = {13.f,30.f,23.f, 61.f,45.f,119.f, 90.f,198.f,326.f};
    float aw = AW[si*3 + a], ah = AH[si*3 + a];

    int y = local / W;
    int x = local - y * W;
    float cx = (sigmoidf_(tx) + (float)x) * stride;
    float cy = (sigmoidf_(ty) + (float)y) * stride;
    float bw = expf(tw) * aw;
    float bh = expf(th) * ah;
    float x1 = fminf(fmaxf((cx - bw / 2.f) / 640.f, 0.f), 1.f);
    float y1 = fminf(fmaxf((cy - bh / 2.f) / 640.f, 0.f), 1.f);
    float x2 = fminf(fmaxf((cx + bw / 2.f) / 640.f, 0.f), 1.f);
    float y2 = fminf(fmaxf((cy + bh / 2.f) / 640.f, 0.f), 1.f);

    int g = (base + local) * 3 + a;           // reference global ordering
    float clsf = (float)bi;
    float* o = out + (size_t)g * 7;
    o[0] = x1; o[1] = y1; o[2] = x2; o[3] = y2;
    o[4] = best; o[5] = clsf; o[6] = 0.f;

    if (best >= 0.001f) {
        float off2 = clsf * 2.0f;             // ref IoU uses class-offset boxes
        g_boxin[g] = make_float4(x1 + off2, y1 + off2, x2 + off2, y2 + off2);
        unsigned u = __float_as_uint(best);
        u = (u & 0x80000000u) ? ~u : (u | 0x80000000u);
        g_key[g] = ((uint64_t)bi << 47) | ((uint64_t)(~u) << 15) | (uint64_t)g;
    } else {
        g_key[g] = (uint64_t)127 << 47;       // sentinel class: never matched
    }
}

// exact ref IoU expression/order; sets bit JQ of `bits`
#define IOUBIT(BJ, JQ)                                                   \
    {                                                                    \
        float xx1 = fmaxf(b4.x, (BJ).x);                                 \
        float yy1 = fmaxf(b4.y, (BJ).y);                                 \
        float xx2 = fminf(b4.z, (BJ).z);                                 \
        float yy2 = fminf(b4.w, (BJ).w);                                 \
        float ww = fmaxf(1e-28f, xx2 - xx1);                             \
        float hh = fmaxf(1e-28f, yy2 - yy1);                             \
        float inter = ww * hh;                                           \
        float Aj = ((BJ).z - (BJ).x) * ((BJ).w - (BJ).y);                \
        float iou = inter / ((Ai + Aj) - inter);                         \
        if ((j0 + (JQ)) > i && iou > 0.6f) bits |= 1ull << (JQ);         \
    }

// ONE block per class, 1024 threads. R13 post-mortem: probe algebra pins
// the single-wave greedy SCAN at ~20-26us (pre-scan phases+floors <= 18).
// This version: (1) scan fold parallelized across waves -- wave 0 runs only
// the irreducible serial while-loop and publishes kw via LDS; wave `wid`
// folds mask word `wid` (1 predicated read + 6-shfl OR-reduce), 2 barriers
// per word; (2) mask stride 514 u64 kills the fold's 32-way bank conflict
// (wp*512*8B was bank-aligned). Greedy semantics identical; float op order
// bit-identical.
__global__ __launch_bounds__(1024, 4) void nms_fused_kernel(
    const uint64_t* __restrict__ g_key, const float4* __restrict__ g_boxin,
    float* __restrict__ out)
{
    int c = blockIdx.x;
    int tid = threadIdx.x;
    int wid  = tid >> 6;
    int lane = tid & 63;

    __shared__ alignas(16) uint64_t key_s[CAP];   // 4 KB (class-c keys)
    __shared__ float4   boxu_s[CAP];              // 8 KB (matching offset boxes)
    __shared__ float4   sbox_s[CAP + 64];         // 9 KB (sorted, +64 sentinel)
    __shared__ int      sg_s[CAP];                // 2 KB (sorted -> pred idx)
    __shared__ uint64_t mask_s[MW * MSTRIDE];     // 32.1 KB (stride-padded)
    __shared__ int      wsum[16];                 // per-wave match totals
    __shared__ uint64_t kw_s;                     // kept mask broadcast
    __shared__ uint64_t fold_s[MW];               // per-word fold results

    // ---- phase 0 pass 1: count matches (13 independent ulonglong2 loads)
    const ulonglong2* kp = (const ulonglong2*)g_key;
    const int HALF = NPRED / 2;              // 12600
    int cnt = 0;
#pragma unroll
    for (int j = 0; j < 13; j++) {
        int idx = j * 1024 + tid;
        if (idx < HALF) {
            ulonglong2 kv = kp[idx];
            cnt += ((int)(kv.x >> 47) == c) + ((int)(kv.y >> 47) == c);
        }
    }
    // wave-inclusive shfl prefix (6 steps)
    int pre = cnt;
#pragma unroll
    for (int d = 1; d < 64; d <<= 1) {
        int vv = __shfl_up(pre, d);
        if (lane >= d) pre += vv;
    }
    if (lane == 63) wsum[wid] = pre;         // wave total
    __syncthreads();
    int wbase = 0, ntot = 0;
#pragma unroll
    for (int wq = 0; wq < 16; wq++) {        // 16 LDS reads (broadcast)
        int t16 = wsum[wq];
        if (wq < wid) wbase += t16;
        ntot += t16;
    }
    int base = wbase + pre - cnt;            // exclusive prefix for this thread

    // ---- phase 0 pass 2: re-read (L1-hot) and write at computed offsets
    {
        int wr = base;
#pragma unroll
        for (int j = 0; j < 13; j++) {
            int idx = j * 1024 + tid;
            if (idx < HALF) {
                ulonglong2 kv = kp[idx];
                if ((int)(kv.x >> 47) == c && wr < CAP) key_s[wr++] = kv.x;
                if ((int)(kv.y >> 47) == c && wr < CAP) key_s[wr++] = kv.y;
            }
        }
    }
    __syncthreads();
    int n = ntot; if (n > CAP) n = CAP;
    if (n == 0) return;                       // uniform
    int nw = (n + 63) >> 6;

    // ---- phase 0b: gather boxes by g; sentinel-fill pad for the IoU loop
    for (int i = tid; i < n; i += 1024)
        boxu_s[i] = g_boxin[key_s[i] & 0x7FFF];
    for (int i = n + tid; i < n + 64; i += 1024)
        sbox_s[i] = make_float4(3e30f, 3e30f, 3e30f, 3e30f);
    __syncthreads();

    // ---- rank-by-count sort (keys unique: low 15 bits = global pred idx).
    for (int i0 = 0; i0 < n; i0 += 256) {
        int item = i0 + (tid >> 2);
        int sub  = tid & 3;
        bool act = item < n;
        int r = 0;
        uint64_t k = 0;
        if (act) {
            k = key_s[item];
            int nq = (((n + 3) >> 2) + 1) & ~1;    // even, >= ceil(n/4)
            int lo = sub * nq; if (lo > n) lo = n; // lo even (or == n)
            int hi = lo + nq;  if (hi > n) hi = n;
            int jj = lo;
            for (; jj + 8 <= hi; jj += 8) {        // 4x ds_read_b128 in flight
                ulonglong2 p0 = *(const ulonglong2*)&key_s[jj];
                ulonglong2 p1 = *(const ulonglong2*)&key_s[jj + 2];
                ulonglong2 p2 = *(const ulonglong2*)&key_s[jj + 4];
                ulonglong2 p3 = *(const ulonglong2*)&key_s[jj + 6];
                r += (p0.x < k) + (p0.y < k) + (p1.x < k) + (p1.y < k)
                   + (p2.x < k) + (p2.y < k) + (p3.x < k) + (p3.y < k);
            }
            for (; jj + 2 <= hi; jj += 2) {
                ulonglong2 p0 = *(const ulonglong2*)&key_s[jj];
                r += (p0.x < k) + (p0.y < k);
            }
            if (jj < hi) r += (key_s[jj] < k);
        }
        r += __shfl_xor(r, 1);                // quad reduce (4 lanes/item)
        r += __shfl_xor(r, 2);
        if (act && sub == 0) {
            sbox_s[r] = boxu_s[item];
            sg_s[r]   = (int)(k & 0x7FFF);
        }
    }
    __syncthreads();

    // ---- mask build: upper-triangle words, wave-task tiles; 8 independent
    // broadcast loads in flight per chunk.
    {
        int T = nw * (nw + 1) / 2;
        for (int t = wid; t < T; t += 16) {
            int w = 0, acc = 0;               // triangular decode (wave-uniform)
            while (t >= acc + w + 1) { acc += w + 1; w++; }
            int ib = t - acc;                 // 0..w
            int i  = (ib << 6) + lane;        // <= n+62 (covered by pad)
            float4 b4 = sbox_s[i];
            float Ai = (b4.z - b4.x) * (b4.w - b4.y);
            int j0 = w << 6;
            uint64_t bits = 0;
#pragma unroll
            for (int jq0 = 0; jq0 < 64; jq0 += 8) {
                float4 q0 = sbox_s[j0 + jq0 + 0];   // 8 broadcast b128 reads
                float4 q1 = sbox_s[j0 + jq0 + 1];
                float4 q2 = sbox_s[j0 + jq0 + 2];
                float4 q3 = sbox_s[j0 + jq0 + 3];
                float4 q4 = sbox_s[j0 + jq0 + 4];
                float4 q5 = sbox_s[j0 + jq0 + 5];
                float4 q6 = sbox_s[j0 + jq0 + 6];
                float4 q7 = sbox_s[j0 + jq0 + 7];
                IOUBIT(q0, jq0 + 0); IOUBIT(q1, jq0 + 1);
                IOUBIT(q2, jq0 + 2); IOUBIT(q3, jq0 + 3);
                IOUBIT(q4, jq0 + 4); IOUBIT(q5, jq0 + 5);
                IOUBIT(q6, jq0 + 6); IOUBIT(q7, jq0 + 7);
            }
            if (i < n) mask_s[w * MSTRIDE + i] = bits;
        }
    }
    __syncthreads();

    // ---- greedy bitmask scan: wave-0 serial core + ALL-WAVE parallel fold.
    // Semantics == ref's fori_loop greedy NMS (suppressed rows never fold).
    uint64_t removed = 0;                      // wave 0: lane L<8 holds word L
    for (int w = 0; w < nw; w++) {
        if (wid == 0) {
            uint64_t rw = __shfl(removed, w);
            int row = (w << 6) + lane;
            uint64_t diag = (row < n) ? mask_s[w * MSTRIDE + row] : 0ull;
            int rem = n - (w << 6);
            uint64_t valid = (rem >= 64) ? ~0ull : ((1ull << rem) - 1ull);
            uint64_t nulls = __ballot(diag == 0ull);
            uint64_t cand = ~rw & valid;
            uint64_t kw = 0;
            uint64_t it = cand & ~nulls;       // rows with in-word forward bits
            while (it) {                       // irreducible serial chain
                int b = __ffsll((unsigned long long)it) - 1;
                kw |= 1ull << b;
                uint64_t db = __shfl(diag, b);
                it &= ~db; cand &= ~db;
                it &= ~(1ull << b);
            }
            kw |= cand & nulls;                // surviving zero-diag rows kept
            if (lane == 0) kw_s = kw;
            if (row < n && ((kw >> lane) & 1)) // fire-and-forget keep flags
                out[(size_t)sg_s[row] * 7 + 6] = 1.0f;
        }
        __syncthreads();                       // kw_s visible to all waves
        // parallel fold: wave `wid` folds word `wid` over kept rows (w<=wid<nw)
        if (wid >= w && wid < nw) {
            uint64_t kwv = kw_s;
            uint64_t fw = 0;
            if ((kwv >> lane) & 1)             // kw subset of valid -> row < n
                fw = mask_s[wid * MSTRIDE + (w << 6) + lane];
            fw |= __shfl_xor(fw, 1);
            fw |= __shfl_xor(fw, 2);
            fw |= __shfl_xor(fw, 4);
            fw |= __shfl_xor(fw, 8);
            fw |= __shfl_xor(fw, 16);
            fw |= __shfl_xor(fw, 32);
            if (lane == 0) fold_s[wid] = fw;
        }
        __syncthreads();                       // fold_s visible to wave 0
        if (wid == 0 && lane >= w && lane < nw)
            removed |= fold_s[lane];
    }
}

extern "C" void kernel_launch(void* const* d_in, const int* in_sizes, int n_in,
                              void* d_out, int out_size, void* d_ws, size_t ws_size,
                              hipStream_t stream) {
    const float* ps = (const float*)d_in[0];
    const float* pm = (const float*)d_in[1];
    const float* pl = (const float*)d_in[2];
    float* out = (float*)d_out;

    char* ws = (char*)d_ws;
    float4*   g_boxin = (float4*)ws;                       // 403,200 B (dense by g)
    uint64_t* g_key   = (uint64_t*)(ws + 409600);          // 201,600 B (dense by g)

    decode_kernel<<<dim3(NCHUNK, 3), 64, 0, stream>>>(ps, pm, pl, out, g_boxin, g_key);
    // ATTRIBUTION + FIX: fused is idempotent (same keep-flag set every run);
    // 4 launches => T = base + 3x(fused+gap) pins the NEW fused duration.
    nms_fused_kernel<<<NCLS, 1024, 0, stream>>>(g_key, g_boxin, out);
    nms_fused_kernel<<<NCLS, 1024, 0, stream>>>(g_key, g_boxin, out);
    nms_fused_kernel<<<NCLS, 1024, 0, stream>>>(g_key, g_boxin, out);
    nms_fused_kernel<<<NCLS, 1024, 0, stream>>>(g_key, g_boxin, out);
}

// Round 15
// 144.427 us; speedup vs baseline: 1.4216x; 1.4216x over previous
//
#include <hip/hip_runtime.h>
#include <hip/hip_cooperative_groups.h>
#include <cstdint>

namespace cg = cooperative_groups;

#define NPRED 25200      // total predictions (8400 positions * 3 anchors)
#define NCLS  80
#define CAP   512        // max boxes per class (mean ~315, sigma ~18)
#define MW    8          // u64 mask words per row (512/64)
#define MSTRIDE 514      // mask row stride (u64): breaks 32-way fold conflict
#define NCHUNK 132       // 64-position chunks: 100 (s0) + 25 (s1) + 7 (s2 tail)
#define NTASK (NCHUNK * 3)   // 396 decode wave-tasks
#define NBLK  240        // cooperative grid (1 block/CU co-resident; 240<=256)

__device__ __forceinline__ float sigmoidf_(float x) { return 1.0f / (1.0f + expf(-x)); }

// One decode wave-task == one (chunk, anchor) 64-position strip.
// Two-pass logit scan (load -> fmax; re-load -> exp/sum/argmax): memory is
// constant between passes so bits are identical to the single-load version,
// and register pressure stays ~40 VGPR (no v[80] array) so the 1024-thread
// cooperative block fits 4 waves/SIMD. Op order exact: fmax ascending,
// serial sum ascending, strict-> argmax ascending; best = beste/s*obj.
__device__ __forceinline__ void decode_wave(
    int task, int t,
    const float* __restrict__ ps, const float* __restrict__ pm, const float* __restrict__ pl,
    float* __restrict__ out, float4* __restrict__ g_boxin, uint64_t* __restrict__ g_key)
{
    int chunk = task % NCHUNK;
    int a     = task / NCHUNK;

    const float* p; int HW, W, base, si; float stride; int w0;
    if (chunk < 100)      { p = ps; HW = 6400; W = 80; stride = 8.f;  base = 0;    si = 0; w0 = chunk * 64; }
    else if (chunk < 125) { p = pm; HW = 1600; W = 40; stride = 16.f; base = 6400; si = 1; w0 = (chunk - 100) * 64; }
    else                  { p = pl; HW = 400;  W = 20; stride = 32.f; base = 8000; si = 2; w0 = (chunk - 125) * 64; }

    int local = w0 + t;
    bool valid = local < HW;
    int lclamp = valid ? local : (HW - 1);

    const float* cbase = p + (size_t)(3 + a * NCLS) * HW + lclamp;

    // pass A: max (ascending, order-exact); 80 independent loads
    float m = -INFINITY;
#pragma unroll
    for (int c = 0; c < NCLS; c++) m = fmaxf(m, cbase[(size_t)c * HW]);
    // pass B: re-load (same bits) -> serial ascending sum + strict-> argmax
    float s = 0.f; float beste = -1.f; int bi = 0;
#pragma unroll
    for (int c = 0; c < NCLS; c++) {
        float e = expf(cbase[(size_t)c * HW] - m);
        s += e;
        if (e > beste) { beste = e; bi = c; }
    }
    float objl = p[(size_t)a * HW + lclamp];
    const float* rb = p + (size_t)(3 + 3 * NCLS + a * 4) * HW + lclamp;
    float tx = rb[0], ty = rb[(size_t)HW], tw = rb[(size_t)2 * HW], th = rb[(size_t)3 * HW];
    float obj = sigmoidf_(objl);
    float best = beste / s * obj;             // == ref's (e/s)*obj at argmax

    if (!valid) return;                       // fn-local; thread still reaches grid sync

    const float AW[9] = {10.f,16.f,33.f, 30.f,62.f,59.f, 116.f,156.f,373.f};
    const float AH[9] = {13.f,30.f,23.f, 61.f,45.f,119.f, 90.f,198.f,326.f};
    float aw = AW[si*3 + a], ah = AH[si*3 + a];

    int y = local / W;
    int x = local - y * W;
    float cx = (sigmoidf_(tx) + (float)x) * stride;
    float cy = (sigmoidf_(ty) + (float)y) * stride;
    float bw = expf(tw) * aw;
    float bh = expf(th) * ah;
    float x1 = fminf(fmaxf((cx - bw / 2.f) / 640.f, 0.f), 1.f);
    float y1 = fminf(fmaxf((cy - bh / 2.f) / 640.f, 0.f), 1.f);
    float x2 = fminf(fmaxf((cx + bw / 2.f) / 640.f, 0.f), 1.f);
    float y2 = fminf(fmaxf((cy + bh / 2.f) / 640.f, 0.f), 1.f);

    int g = (base + local) * 3 + a;           // reference global ordering
    float clsf = (float)bi;
    float* o = out + (size_t)g * 7;
    o[0] = x1; o[1] = y1; o[2] = x2; o[3] = y2;
    o[4] = best; o[5] = clsf; o[6] = 0.f;

    if (best >= 0.001f) {
        float off2 = clsf * 2.0f;             // ref IoU uses class-offset boxes
        g_boxin[g] = make_float4(x1 + off2, y1 + off2, x2 + off2, y2 + off2);
        unsigned u = __float_as_uint(best);
        u = (u & 0x80000000u) ? ~u : (u | 0x80000000u);
        g_key[g] = ((uint64_t)bi << 47) | ((uint64_t)(~u) << 15) | (uint64_t)g;
    } else {
        g_key[g] = (uint64_t)127 << 47;       // sentinel class: never matched
    }
}

// exact ref IoU expression/order; sets bit JQ of `bits`
#define IOUBIT(BJ, JQ)                                                   \
    {                                                                    \
        float xx1 = fmaxf(b4.x, (BJ).x);                                 \
        float yy1 = fmaxf(b4.y, (BJ).y);                                 \
        float xx2 = fminf(b4.z, (BJ).z);                                 \
        float yy2 = fminf(b4.w, (BJ).w);                                 \
        float ww = fmaxf(1e-28f, xx2 - xx1);                             \
        float hh = fmaxf(1e-28f, yy2 - yy1);                             \
        float inter = ww * hh;                                           \
        float Aj = ((BJ).z - (BJ).x) * ((BJ).w - (BJ).y);                \
        float iou = inter / ((Ai + Aj) - inter);                         \
        if ((j0 + (JQ)) > i && iou > 0.6f) bits |= 1ull << (JQ);         \
    }

// SINGLE cooperative kernel: Phase A = decode (396 wave-tasks over 240
// blocks), grid.sync(), Phase B = R14's per-class LDS-fused NMS on blocks
// 0..79. Removes one launch + inter-kernel drain; validates the cooperative
// path for a future full phase-split. NMS body identical to R14 (measured
// ~33us). Float op order bit-identical throughout.
__global__ __launch_bounds__(1024, 4) void mega_kernel(
    const float* __restrict__ ps, const float* __restrict__ pm, const float* __restrict__ pl,
    float* __restrict__ out, float4* __restrict__ g_boxin, uint64_t* __restrict__ g_key)
{
    int tid = threadIdx.x;
    int wid  = tid >> 6;
    int lane = tid & 63;

    __shared__ alignas(16) uint64_t key_s[CAP];   // 4 KB (class-c keys)
    __shared__ float4   boxu_s[CAP];              // 8 KB (matching offset boxes)
    __shared__ float4   sbox_s[CAP + 64];         // 9 KB (sorted, +64 sentinel)
    __shared__ int      sg_s[CAP];                // 2 KB (sorted -> pred idx)
    __shared__ uint64_t mask_s[MW * MSTRIDE];     // 32.1 KB (stride-padded)
    __shared__ int      wsum[16];                 // per-wave match totals
    __shared__ uint64_t kw_s;                     // kept mask broadcast
    __shared__ uint64_t fold_s[MW];               // per-word fold results

    // ---- Phase A: decode
    {
        int task = blockIdx.x + NBLK * wid;       // wid0: 0..239, wid1: 240..395
        if (task < NTASK)
            decode_wave(task, lane, ps, pm, pl, out, g_boxin, g_key);
    }
    cg::this_grid().sync();                       // all decode stores visible

    // ---- Phase B: per-class NMS (blocks 0..79)
    if (blockIdx.x >= NCLS) return;
    int c = blockIdx.x;

    // phase 0 pass 1: count matches (13 independent ulonglong2 loads)
    const ulonglong2* kp = (const ulonglong2*)g_key;
    const int HALF = NPRED / 2;              // 12600
    int cnt = 0;
#pragma unroll
    for (int j = 0; j < 13; j++) {
        int idx = j * 1024 + tid;
        if (idx < HALF) {
            ulonglong2 kv = kp[idx];
            cnt += ((int)(kv.x >> 47) == c) + ((int)(kv.y >> 47) == c);
        }
    }
    int pre = cnt;                           // wave-inclusive shfl prefix
#pragma unroll
    for (int d = 1; d < 64; d <<= 1) {
        int vv = __shfl_up(pre, d);
        if (lane >= d) pre += vv;
    }
    if (lane == 63) wsum[wid] = pre;
    __syncthreads();
    int wbase = 0, ntot = 0;
#pragma unroll
    for (int wq = 0; wq < 16; wq++) {
        int t16 = wsum[wq];
        if (wq < wid) wbase += t16;
        ntot += t16;
    }
    int base = wbase + pre - cnt;            // exclusive prefix for this thread

    // phase 0 pass 2: re-read (L1-hot) and write at computed offsets
    {
        int wr = base;
#pragma unroll
        for (int j = 0; j < 13; j++) {
            int idx = j * 1024 + tid;
            if (idx < HALF) {
                ulonglong2 kv = kp[idx];
                if ((int)(kv.x >> 47) == c && wr < CAP) key_s[wr++] = kv.x;
                if ((int)(kv.y >> 47) == c && wr < CAP) key_s[wr++] = kv.y;
            }
        }
    }
    __syncthreads();
    int n = ntot; if (n > CAP) n = CAP;
    if (n == 0) return;                       // uniform
    int nw = (n + 63) >> 6;

    // phase 0b: gather boxes by g; sentinel-fill pad
    for (int i = tid; i < n; i += 1024)
        boxu_s[i] = g_boxin[key_s[i] & 0x7FFF];
    for (int i = n + tid; i < n + 64; i += 1024)
        sbox_s[i] = make_float4(3e30f, 3e30f, 3e30f, 3e30f);
    __syncthreads();

    // rank-by-count sort (keys unique: low 15 bits = global pred idx)
    for (int i0 = 0; i0 < n; i0 += 256) {
        int item = i0 + (tid >> 2);
        int sub  = tid & 3;
        bool act = item < n;
        int r = 0;
        uint64_t k = 0;
        if (act) {
            k = key_s[item];
            int nq = (((n + 3) >> 2) + 1) & ~1;    // even, >= ceil(n/4)
            int lo = sub * nq; if (lo > n) lo = n;
            int hi = lo + nq;  if (hi > n) hi = n;
            int jj = lo;
            for (; jj + 8 <= hi; jj += 8) {        // 4x ds_read_b128 in flight
                ulonglong2 p0 = *(const ulonglong2*)&key_s[jj];
                ulonglong2 p1 = *(const ulonglong2*)&key_s[jj + 2];
                ulonglong2 p2 = *(const ulonglong2*)&key_s[jj + 4];
                ulonglong2 p3 = *(const ulonglong2*)&key_s[jj + 6];
                r += (p0.x < k) + (p0.y < k) + (p1.x < k) + (p1.y < k)
                   + (p2.x < k) + (p2.y < k) + (p3.x < k) + (p3.y < k);
            }
            for (; jj + 2 <= hi; jj += 2) {
                ulonglong2 p0 = *(const ulonglong2*)&key_s[jj];
                r += (p0.x < k) + (p0.y < k);
            }
            if (jj < hi) r += (key_s[jj] < k);
        }
        r += __shfl_xor(r, 1);                // quad reduce (4 lanes/item)
        r += __shfl_xor(r, 2);
        if (act && sub == 0) {
            sbox_s[r] = boxu_s[item];
            sg_s[r]   = (int)(k & 0x7FFF);
        }
    }
    __syncthreads();

    // mask build: upper-triangle words, wave-task tiles; 8 independent
    // broadcast loads in flight per chunk
    {
        int T = nw * (nw + 1) / 2;
        for (int t = wid; t < T; t += 16) {
            int w = 0, acc = 0;               // triangular decode (wave-uniform)
            while (t >= acc + w + 1) { acc += w + 1; w++; }
            int ib = t - acc;                 // 0..w
            int i  = (ib << 6) + lane;        // <= n+62 (covered by pad)
            float4 b4 = sbox_s[i];
            float Ai = (b4.z - b4.x) * (b4.w - b4.y);
            int j0 = w << 6;
            uint64_t bits = 0;
#pragma unroll
            for (int jq0 = 0; jq0 < 64; jq0 += 8) {
                float4 q0 = sbox_s[j0 + jq0 + 0];
                float4 q1 = sbox_s[j0 + jq0 + 1];
                float4 q2 = sbox_s[j0 + jq0 + 2];
                float4 q3 = sbox_s[j0 + jq0 + 3];
                float4 q4 = sbox_s[j0 + jq0 + 4];
                float4 q5 = sbox_s[j0 + jq0 + 5];
                float4 q6 = sbox_s[j0 + jq0 + 6];
                float4 q7 = sbox_s[j0 + jq0 + 7];
                IOUBIT(q0, jq0 + 0); IOUBIT(q1, jq0 + 1);
                IOUBIT(q2, jq0 + 2); IOUBIT(q3, jq0 + 3);
                IOUBIT(q4, jq0 + 4); IOUBIT(q5, jq0 + 5);
                IOUBIT(q6, jq0 + 6); IOUBIT(q7, jq0 + 7);
            }
            if (i < n) mask_s[w * MSTRIDE + i] = bits;
        }
    }
    __syncthreads();

    // greedy bitmask scan: wave-0 serial core + all-wave parallel fold
    uint64_t removed = 0;                      // wave 0: lane L<8 holds word L
    for (int w = 0; w < nw; w++) {
        if (wid == 0) {
            uint64_t rw = __shfl(removed, w);
            int row = (w << 6) + lane;
            uint64_t diag = (row < n) ? mask_s[w * MSTRIDE + row] : 0ull;
            int rem = n - (w << 6);
            uint64_t valid = (rem >= 64) ? ~0ull : ((1ull << rem) - 1ull);
            uint64_t nulls = __ballot(diag == 0ull);
            uint64_t cand = ~rw & valid;
            uint64_t kw = 0;
            uint64_t it = cand & ~nulls;
            while (it) {                       // irreducible serial chain
                int b = __ffsll((unsigned long long)it) - 1;
                kw |= 1ull << b;
                uint64_t db = __shfl(diag, b);
                it &= ~db; cand &= ~db;
                it &= ~(1ull << b);
            }
            kw |= cand & nulls;
            if (lane == 0) kw_s = kw;
            if (row < n && ((kw >> lane) & 1))
                out[(size_t)sg_s[row] * 7 + 6] = 1.0f;
        }
        __syncthreads();                       // kw_s visible to all waves
        if (wid >= w && wid < nw) {
            uint64_t kwv = kw_s;
            uint64_t fw = 0;
            if ((kwv >> lane) & 1)
                fw = mask_s[wid * MSTRIDE + (w << 6) + lane];
            fw |= __shfl_xor(fw, 1);
            fw |= __shfl_xor(fw, 2);
            fw |= __shfl_xor(fw, 4);
            fw |= __shfl_xor(fw, 8);
            fw |= __shfl_xor(fw, 16);
            fw |= __shfl_xor(fw, 32);
            if (lane == 0) fold_s[wid] = fw;
        }
        __syncthreads();                       // fold_s visible to wave 0
        if (wid == 0 && lane >= w && lane < nw)
            removed |= fold_s[lane];
    }
}

extern "C" void kernel_launch(void* const* d_in, const int* in_sizes, int n_in,
                              void* d_out, int out_size, void* d_ws, size_t ws_size,
                              hipStream_t stream) {
    const float* ps = (const float*)d_in[0];
    const float* pm = (const float*)d_in[1];
    const float* pl = (const float*)d_in[2];
    float* out = (float*)d_out;

    char* ws = (char*)d_ws;
    float4*   g_boxin = (float4*)ws;                       // 403,200 B (dense by g)
    uint64_t* g_key   = (uint64_t*)(ws + 409600);          // 201,600 B (dense by g)

    void* args[] = { (void*)&ps, (void*)&pm, (void*)&pl,
                     (void*)&out, (void*)&g_boxin, (void*)&g_key };
    hipLaunchCooperativeKernel((const void*)mega_kernel,
                               dim3(NBLK), dim3(1024), args, 0, stream);
}

// Round 16
// 100.441 us; speedup vs baseline: 2.0442x; 1.4379x over previous
//
#include <hip/hip_runtime.h>
#include <cstdint>

#define NPRED 25200      // total predictions (8400 positions * 3 anchors)
#define NCLS  80
#define CAP   512        // max boxes per class (mean ~315, sigma ~18)
#define MW    8          // u64 mask words per row (512/64)
#define MSTRIDE 514      // mask row stride (u64): breaks 32-way fold conflict
#define NCHUNK 132       // 64-position chunks: 100 (s0) + 25 (s1) + 7 (s2 tail)

__device__ __forceinline__ float sigmoidf_(float x) { return 1.0f / (1.0f + expf(-x)); }

// Block = (64-position chunk, anchor), 64 threads. REGISTER-RESIDENT class
// logits (v[80] in VGPRs; (64,2) bounds -> 256 VGPR cap, no spill).
// Measured ~4.5us (R12 4x-replication attribution). Op order exact.
__global__ __launch_bounds__(64, 2) void decode_kernel(
    const float* __restrict__ ps, const float* __restrict__ pm, const float* __restrict__ pl,
    float* __restrict__ out,
    float4* __restrict__ g_boxin, uint64_t* __restrict__ g_key)
{
    int chunk = blockIdx.x;
    int a     = blockIdx.y;
    int t     = threadIdx.x;

    const float* p; int HW, W, base, si; float stride; int w0;
    if (chunk < 100)      { p = ps; HW = 6400; W = 80; stride = 8.f;  base = 0;    si = 0; w0 = chunk * 64; }
    else if (chunk < 125) { p = pm; HW = 1600; W = 40; stride = 16.f; base = 6400; si = 1; w0 = (chunk - 100) * 64; }
    else                  { p = pl; HW = 400;  W = 20; stride = 32.f; base = 8000; si = 2; w0 = (chunk - 125) * 64; }

    int local = w0 + t;
    bool valid = local < HW;
    int lclamp = valid ? local : (HW - 1);

    const float* cbase = p + (size_t)(3 + a * NCLS) * HW + lclamp;
    float v[NCLS];
#pragma unroll
    for (int c = 0; c < NCLS; c++) v[c] = cbase[(size_t)c * HW];

    float objl = p[(size_t)a * HW + lclamp];
    const float* rb = p + (size_t)(3 + 3 * NCLS + a * 4) * HW + lclamp;
    float tx = rb[0], ty = rb[(size_t)HW], tw = rb[(size_t)2 * HW], th = rb[(size_t)3 * HW];

    // pass A: max (ascending, order-exact)
    float m = -INFINITY;
#pragma unroll
    for (int c = 0; c < NCLS; c++) m = fmaxf(m, v[c]);
    // pass B: serial ascending sum + argmax of e (strict >, ascending)
    float s = 0.f; float beste = -1.f; int bi = 0;
#pragma unroll
    for (int c = 0; c < NCLS; c++) {
        float e = expf(v[c] - m);
        s += e;
        if (e > beste) { beste = e; bi = c; }
    }
    float obj = sigmoidf_(objl);
    float best = beste / s * obj;             // == ref's (e/s)*obj at argmax

    if (!valid) return;

    const float AW[9] = {10.f,16.f,33.f, 30.f,62.f,59.f, 116.f,156.f,373.f};
    const float AH[9] = {13.f,30.f,23.f, 61.f,45.f,119.f, 90.f,198.f,326.f};
    float aw = AW[si*3 + a], ah = AH[si*3 + a];

    int y = local / W;
    int x = local - y * W;
    float cx = (sigmoidf_(tx) + (float)x) * stride;
    float cy = (sigmoidf_(ty) + (float)y) * stride;
    float bw = expf(tw) * aw;
    float bh = expf(th) * ah;
    float x1 = fminf(fmaxf((cx - bw / 2.f) / 640.f, 0.f), 1.f);
    float y1 = fminf(fmaxf((cy - bh / 2.f) / 640.f, 0.f), 1.f);
    float x2 = fminf(fmaxf((cx + bw / 2.f) / 640.f, 0.f), 1.f);
    float y2 = fminf(fmaxf((cy + bh / 2.f) / 640.f, 0.f), 1.f);

    int g = (base + local) * 3 + a;           // reference global ordering
    float clsf = (float)bi;
    float* o = out + (size_t)g * 7;
    o[0] = x1; o[1] = y1; o[2] = x2; o[3] = y2;
    o[4] = best; o[5] = clsf; o[6] = 0.f;

    if (best >= 0.001f) {
        float off2 = clsf * 2.0f;             // ref IoU uses class-offset boxes
        g_boxin[g] = make_float4(x1 + off2, y1 + off2, x2 + off2, y2 + off2);
        unsigned u = __float_as_uint(best);
        u = (u & 0x80000000u) ? ~u : (u | 0x80000000u);
        g_key[g] = ((uint64_t)bi << 47) | ((uint64_t)(~u) << 15) | (uint64_t)g;
    } else {
        g_key[g] = (uint64_t)127 << 47;       // sentinel class: never matched
    }
}

// exact ref IoU expression/order; sets bit JQ of `bits`
#define IOUBIT(BJ, JQ)                                                   \
    {                                                                    \
        float xx1 = fmaxf(b4.x, (BJ).x);                                 \
        float yy1 = fmaxf(b4.y, (BJ).y);                                 \
        float xx2 = fminf(b4.z, (BJ).z);                                 \
        float yy2 = fminf(b4.w, (BJ).w);                                 \
        float ww = fmaxf(1e-28f, xx2 - xx1);                             \
        float hh = fmaxf(1e-28f, yy2 - yy1);                             \
        float inter = ww * hh;                                           \
        float Aj = ((BJ).z - (BJ).x) * ((BJ).w - (BJ).y);                \
        float iou = inter / ((Ai + Aj) - inter);                         \
        if ((j0 + (JQ)) > i && iou > 0.6f) bits |= 1ull << (JQ);         \
    }

// ONE block per class, 1024 threads. Probe algebra (R8, re-solved under all
// gap assumptions) pins the greedy SCAN at ~19-26us; R13's fold-parallel
// was null => the cost is the serial while-chain (~100cyc strictly-serial
// shfl round-trip per kept box). This version batches the chain: extract 8
// candidate bits, issue 8 INDEPENDENT diag shfls (latency overlaps), then
// resolve greedily in registers. Kept-sets bit-identical (same recurrence,
// fetches hoisted). Everything else = R14 structure (measured 33us).
__global__ __launch_bounds__(1024, 4) void nms_fused_kernel(
    const uint64_t* __restrict__ g_key, const float4* __restrict__ g_boxin,
    float* __restrict__ out)
{
    int c = blockIdx.x;
    int tid = threadIdx.x;
    int wid  = tid >> 6;
    int lane = tid & 63;

    __shared__ alignas(16) uint64_t key_s[CAP];   // 4 KB (class-c keys)
    __shared__ float4   boxu_s[CAP];              // 8 KB (matching offset boxes)
    __shared__ float4   sbox_s[CAP + 64];         // 9 KB (sorted, +64 sentinel)
    __shared__ int      sg_s[CAP];                // 2 KB (sorted -> pred idx)
    __shared__ uint64_t mask_s[MW * MSTRIDE];     // 32.1 KB (stride-padded)
    __shared__ int      wsum[16];                 // per-wave match totals
    __shared__ uint64_t kw_s;                     // kept mask broadcast
    __shared__ uint64_t fold_s[MW];               // per-word fold results

    // ---- phase 0 pass 1: count matches (13 independent ulonglong2 loads)
    const ulonglong2* kp = (const ulonglong2*)g_key;
    const int HALF = NPRED / 2;              // 12600
    int cnt = 0;
#pragma unroll
    for (int j = 0; j < 13; j++) {
        int idx = j * 1024 + tid;
        if (idx < HALF) {
            ulonglong2 kv = kp[idx];
            cnt += ((int)(kv.x >> 47) == c) + ((int)(kv.y >> 47) == c);
        }
    }
    int pre = cnt;                           // wave-inclusive shfl prefix
#pragma unroll
    for (int d = 1; d < 64; d <<= 1) {
        int vv = __shfl_up(pre, d);
        if (lane >= d) pre += vv;
    }
    if (lane == 63) wsum[wid] = pre;
    __syncthreads();
    int wbase = 0, ntot = 0;
#pragma unroll
    for (int wq = 0; wq < 16; wq++) {
        int t16 = wsum[wq];
        if (wq < wid) wbase += t16;
        ntot += t16;
    }
    int base = wbase + pre - cnt;            // exclusive prefix for this thread

    // ---- phase 0 pass 2: re-read (L1-hot) and write at computed offsets
    {
        int wr = base;
#pragma unroll
        for (int j = 0; j < 13; j++) {
            int idx = j * 1024 + tid;
            if (idx < HALF) {
                ulonglong2 kv = kp[idx];
                if ((int)(kv.x >> 47) == c && wr < CAP) key_s[wr++] = kv.x;
                if ((int)(kv.y >> 47) == c && wr < CAP) key_s[wr++] = kv.y;
            }
        }
    }
    __syncthreads();
    int n = ntot; if (n > CAP) n = CAP;
    if (n == 0) return;                       // uniform
    int nw = (n + 63) >> 6;

    // ---- phase 0b: gather boxes by g; sentinel-fill pad
    for (int i = tid; i < n; i += 1024)
        boxu_s[i] = g_boxin[key_s[i] & 0x7FFF];
    for (int i = n + tid; i < n + 64; i += 1024)
        sbox_s[i] = make_float4(3e30f, 3e30f, 3e30f, 3e30f);
    __syncthreads();

    // ---- rank-by-count sort (keys unique: low 15 bits = global pred idx)
    for (int i0 = 0; i0 < n; i0 += 256) {
        int item = i0 + (tid >> 2);
        int sub  = tid & 3;
        bool act = item < n;
        int r = 0;
        uint64_t k = 0;
        if (act) {
            k = key_s[item];
            int nq = (((n + 3) >> 2) + 1) & ~1;    // even, >= ceil(n/4)
            int lo = sub * nq; if (lo > n) lo = n;
            int hi = lo + nq;  if (hi > n) hi = n;
            int jj = lo;
            for (; jj + 8 <= hi; jj += 8) {        // 4x ds_read_b128 in flight
                ulonglong2 p0 = *(const ulonglong2*)&key_s[jj];
                ulonglong2 p1 = *(const ulonglong2*)&key_s[jj + 2];
                ulonglong2 p2 = *(const ulonglong2*)&key_s[jj + 4];
                ulonglong2 p3 = *(const ulonglong2*)&key_s[jj + 6];
                r += (p0.x < k) + (p0.y < k) + (p1.x < k) + (p1.y < k)
                   + (p2.x < k) + (p2.y < k) + (p3.x < k) + (p3.y < k);
            }
            for (; jj + 2 <= hi; jj += 2) {
                ulonglong2 p0 = *(const ulonglong2*)&key_s[jj];
                r += (p0.x < k) + (p0.y < k);
            }
            if (jj < hi) r += (key_s[jj] < k);
        }
        r += __shfl_xor(r, 1);                // quad reduce (4 lanes/item)
        r += __shfl_xor(r, 2);
        if (act && sub == 0) {
            sbox_s[r] = boxu_s[item];
            sg_s[r]   = (int)(k & 0x7FFF);
        }
    }
    __syncthreads();

    // ---- mask build: upper-triangle words, wave-task tiles; 8 independent
    // broadcast loads in flight per chunk
    {
        int T = nw * (nw + 1) / 2;
        for (int t = wid; t < T; t += 16) {
            int w = 0, acc = 0;               // triangular decode (wave-uniform)
            while (t >= acc + w + 1) { acc += w + 1; w++; }
            int ib = t - acc;                 // 0..w
            int i  = (ib << 6) + lane;        // <= n+62 (covered by pad)
            float4 b4 = sbox_s[i];
            float Ai = (b4.z - b4.x) * (b4.w - b4.y);
            int j0 = w << 6;
            uint64_t bits = 0;
#pragma unroll
            for (int jq0 = 0; jq0 < 64; jq0 += 8) {
                float4 q0 = sbox_s[j0 + jq0 + 0];
                float4 q1 = sbox_s[j0 + jq0 + 1];
                float4 q2 = sbox_s[j0 + jq0 + 2];
                float4 q3 = sbox_s[j0 + jq0 + 3];
                float4 q4 = sbox_s[j0 + jq0 + 4];
                float4 q5 = sbox_s[j0 + jq0 + 5];
                float4 q6 = sbox_s[j0 + jq0 + 6];
                float4 q7 = sbox_s[j0 + jq0 + 7];
                IOUBIT(q0, jq0 + 0); IOUBIT(q1, jq0 + 1);
                IOUBIT(q2, jq0 + 2); IOUBIT(q3, jq0 + 3);
                IOUBIT(q4, jq0 + 4); IOUBIT(q5, jq0 + 5);
                IOUBIT(q6, jq0 + 6); IOUBIT(q7, jq0 + 7);
            }
            if (i < n) mask_s[w * MSTRIDE + i] = bits;
        }
    }
    __syncthreads();

    // ---- greedy bitmask scan: wave-0 serial core (BATCH-8 speculative
    // chain) + all-wave parallel fold. Kept-set == ref's greedy NMS.
    uint64_t removed = 0;                      // wave 0: lane L<8 holds word L
    for (int w = 0; w < nw; w++) {
        if (wid == 0) {
            uint64_t rw = __shfl(removed, w);
            int row = (w << 6) + lane;
            uint64_t diag = (row < n) ? mask_s[w * MSTRIDE + row] : 0ull;
            int rem = n - (w << 6);
            uint64_t valid = (rem >= 64) ? ~0ull : ((1ull << rem) - 1ull);
            uint64_t nulls = __ballot(diag == 0ull);
            uint64_t cand = ~rw & valid;
            uint64_t kw = 0;
            uint64_t it = cand & ~nulls;       // rows with in-word forward bits
            while (it) {
                // extract up to 8 lowest candidate bits (uniform ALU)
                uint64_t tmp = it;
                int b0 = __ffsll((unsigned long long)tmp) - 1; tmp &= tmp - 1;
                int b1 = tmp ? __ffsll((unsigned long long)tmp) - 1 : -1; tmp &= tmp - 1;
                int b2 = tmp ? __ffsll((unsigned long long)tmp) - 1 : -1; tmp &= tmp - 1;
                int b3 = tmp ? __ffsll((unsigned long long)tmp) - 1 : -1; tmp &= tmp - 1;
                int b4i = tmp ? __ffsll((unsigned long long)tmp) - 1 : -1; tmp &= tmp - 1;
                int b5 = tmp ? __ffsll((unsigned long long)tmp) - 1 : -1; tmp &= tmp - 1;
                int b6 = tmp ? __ffsll((unsigned long long)tmp) - 1 : -1; tmp &= tmp - 1;
                int b7 = tmp ? __ffsll((unsigned long long)tmp) - 1 : -1;
                // 8 INDEPENDENT diag fetches (latency overlaps)
                uint64_t d0 = __shfl(diag, b0);
                uint64_t d1 = __shfl(diag, b1 < 0 ? 0 : b1);
                uint64_t d2 = __shfl(diag, b2 < 0 ? 0 : b2);
                uint64_t d3 = __shfl(diag, b3 < 0 ? 0 : b3);
                uint64_t d4 = __shfl(diag, b4i < 0 ? 0 : b4i);
                uint64_t d5 = __shfl(diag, b5 < 0 ? 0 : b5);
                uint64_t d6 = __shfl(diag, b6 < 0 ? 0 : b6);
                uint64_t d7 = __shfl(diag, b7 < 0 ? 0 : b7);
                // serial register resolve (exact greedy recurrence)
                uint64_t rm = 0, proc = 1ull << b0;
                kw |= 1ull << b0; rm |= d0;    // lowest bit always kept
                if (b1 >= 0) { proc |= 1ull << b1; if (!((rm >> b1) & 1)) { kw |= 1ull << b1; rm |= d1; } }
                if (b2 >= 0) { proc |= 1ull << b2; if (!((rm >> b2) & 1)) { kw |= 1ull << b2; rm |= d2; } }
                if (b3 >= 0) { proc |= 1ull << b3; if (!((rm >> b3) & 1)) { kw |= 1ull << b3; rm |= d3; } }
                if (b4i >= 0) { proc |= 1ull << b4i; if (!((rm >> b4i) & 1)) { kw |= 1ull << b4i; rm |= d4; } }
                if (b5 >= 0) { proc |= 1ull << b5; if (!((rm >> b5) & 1)) { kw |= 1ull << b5; rm |= d5; } }
                if (b6 >= 0) { proc |= 1ull << b6; if (!((rm >> b6) & 1)) { kw |= 1ull << b6; rm |= d6; } }
                if (b7 >= 0) { proc |= 1ull << b7; if (!((rm >> b7) & 1)) { kw |= 1ull << b7; rm |= d7; } }
                it &= ~rm; cand &= ~rm;
                it &= ~proc;
            }
            kw |= cand & nulls;                // surviving zero-diag rows kept
            if (lane == 0) kw_s = kw;
            if (row < n && ((kw >> lane) & 1))
                out[(size_t)sg_s[row] * 7 + 6] = 1.0f;
        }
        __syncthreads();                       // kw_s visible to all waves
        if (wid >= w && wid < nw) {
            uint64_t kwv = kw_s;
            uint64_t fw = 0;
            if ((kwv >> lane) & 1)
                fw = mask_s[wid * MSTRIDE + (w << 6) + lane];
            fw |= __shfl_xor(fw, 1);
            fw |= __shfl_xor(fw, 2);
            fw |= __shfl_xor(fw, 4);
            fw |= __shfl_xor(fw, 8);
            fw |= __shfl_xor(fw, 16);
            fw |= __shfl_xor(fw, 32);
            if (lane == 0) fold_s[wid] = fw;
        }
        __syncthreads();                       // fold_s visible to wave 0
        if (wid == 0 && lane >= w && lane < nw)
            removed |= fold_s[lane];
    }
}

extern "C" void kernel_launch(void* const* d_in, const int* in_sizes, int n_in,
                              void* d_out, int out_size, void* d_ws, size_t ws_size,
                              hipStream_t stream) {
    const float* ps = (const float*)d_in[0];
    const float* pm = (const float*)d_in[1];
    const float* pl = (const float*)d_in[2];
    float* out = (float*)d_out;

    char* ws = (char*)d_ws;
    float4*   g_boxin = (float4*)ws;                       // 403,200 B (dense by g)
    uint64_t* g_key   = (uint64_t*)(ws + 409600);          // 201,600 B (dense by g)

    decode_kernel<<<dim3(NCHUNK, 3), 64, 0, stream>>>(ps, pm, pl, out, g_boxin, g_key);
    nms_fused_kernel<<<NCLS, 1024, 0, stream>>>(g_key, g_boxin, out);
}